// Round 5
// baseline (86.711 us; speedup 1.0000x reference)
//
#include <hip/hip_runtime.h>
#include <math.h>

#define N_ 2048
#define K_ 512
#define J_ 256

typedef __attribute__((address_space(3))) float       lds_f;
typedef const __attribute__((address_space(1))) float glb_f;

// 2 muls + 1 max3 + 1 min3 per 2 products = 2.0 VALU ops/product.
#define MAX3(acc, a, b) asm("v_max3_f32 %0, %0, %1, %2" : "+v"(acc) : "v"(a), "v"(b))
#define MIN3(acc, a, b) asm("v_min3_f32 %0, %0, %1, %2" : "+v"(acc) : "v"(a), "v"(b))

// Grid 512 x 512 threads (8 waves). NO scalar-memory streaming (R2-R4's ~32us wall):
//   w: VGPRs — 2 j-columns x 64 k per lane (128 regs), loaded once from L2.
//   x: staged ONCE to LDS (16 KB), read as uniform-address ds_read_b128
//      broadcasts (conflict-free). No barriers in the main loop; the 8 waves
//      (one per 64-k chunk) run independently so stalls decorrelate.
// Block tile: 8 n x 128 j x K=512 (8 k-chunk waves). End: partials -> 64 KB LDS,
// one barrier, 8-way merge + bias + coalesced store.
__global__ __launch_bounds__(512) void mam_fused6(
    const float* __restrict__ x, const float* __restrict__ w,
    const float* __restrict__ bias, float* __restrict__ out)
{
    __shared__ __align__(16) float xls[8 * 512];          // 16 KB x tile
    __shared__ __align__(16) float cmb[8 * 8 * 128 * 2];  // 64 KB partials [c][n][jcol][mx,mn]

    const int t    = threadIdx.x;
    const int lane = t & 63;
    const int kc   = __builtin_amdgcn_readfirstlane(t >> 6);   // wave id = k-chunk 0..7

    // XCD-chunked bijective swizzle (512 = 8 * 64): per-XCD x slice ~512 KB + w 512 KB.
    const int wg0 = (int)blockIdx.x;
    const int wg  = (wg0 & 7) * 64 + (wg0 >> 3);
    const int jg  = wg & 1;             // j half (128 cols)
    const int ng  = wg >> 1;            // n group (8 rows), 0..255

    const int n0    = ng * 8;
    const int jbase = jg * 128;

    // Stage x[8][512] once: wave kc stages row kc (2 KB = 2 x 1KB global_load_lds).
    __builtin_amdgcn_global_load_lds(
        (glb_f*)(x + (size_t)(n0 + kc) * K_ + lane * 4),
        (lds_f*)(xls + kc * 512), 16, 0, 0);
    __builtin_amdgcn_global_load_lds(
        (glb_f*)(x + (size_t)(n0 + kc) * K_ + 256 + lane * 4),
        (lds_f*)(xls + kc * 512 + 256), 16, 0, 0);

    // w fragments: lane's 2 j-rows, wave's k-chunk. 32 float4 = 128 VGPRs.
    // L2-resident (512 KB total w); latency overlaps the x staging drain below.
    float4 wreg[2][16];
#pragma unroll
    for (int jj = 0; jj < 2; ++jj) {
        const float4* wp =
            (const float4*)(w + (size_t)(jbase + jj * 64 + lane) * K_ + kc * 64);
#pragma unroll
        for (int g = 0; g < 16; ++g) wreg[jj][g] = wp[g];
    }

    __syncthreads();   // vmcnt(0) drain: x staged + w regs ready

    float mx[8][2], mn[8][2];
#pragma unroll
    for (int n = 0; n < 8; ++n)
#pragma unroll
        for (int jj = 0; jj < 2; ++jj) {
            mx[n][jj] = -__builtin_inff();
            mn[n][jj] =  __builtin_inff();
        }

    // Main loop (fully unrolled, static indexing): per n-row, 16 uniform
    // ds_read_b128 broadcasts + 256 VALU insts. No barriers, no VMEM, no SMEM.
#pragma unroll
    for (int n = 0; n < 8; ++n) {
#pragma unroll
        for (int gb = 0; gb < 4; ++gb) {
            float4 xv[4];
#pragma unroll
            for (int g = 0; g < 4; ++g)
                xv[g] = *(const float4*)&xls[n * 512 + kc * 64 + gb * 16 + g * 4];
#pragma unroll
            for (int g = 0; g < 4; ++g) {
#pragma unroll
                for (int jj = 0; jj < 2; ++jj) {
                    const float4 wv = wreg[jj][gb * 4 + g];
                    const float p0 = xv[g].x * wv.x;
                    const float p1 = xv[g].y * wv.y;
                    const float p2 = xv[g].z * wv.z;
                    const float p3 = xv[g].w * wv.w;
                    MAX3(mx[n][jj], p0, p1); MAX3(mx[n][jj], p2, p3);
                    MIN3(mn[n][jj], p0, p1); MIN3(mn[n][jj], p2, p3);
                }
            }
        }
    }

    // Dump per-chunk partials (waves own disjoint cmb slices; xls untouched).
#pragma unroll
    for (int n = 0; n < 8; ++n)
#pragma unroll
        for (int jj = 0; jj < 2; ++jj) {
            float2 v; v.x = mx[n][jj]; v.y = mn[n][jj];
            *(float2*)&cmb[((kc * 8 + n) * 128 + jj * 64 + lane) * 2] = v;
        }
    __syncthreads();

    // Merge 8 k-chunks: 512 threads x 2 outputs (1024 outputs/block), coalesced store.
#pragma unroll
    for (int i = 0; i < 2; ++i) {
        const int u    = t + i * 512;
        const int n    = u >> 7;
        const int jcol = u & 127;
        float a = -__builtin_inff(), b = __builtin_inff();
#pragma unroll
        for (int c = 0; c < 8; ++c) {
            const float2 p = *(const float2*)&cmb[((c * 8 + n) * 128 + jcol) * 2];
            a = fmaxf(a, p.x);
            b = fminf(b, p.y);
        }
        out[(size_t)(n0 + n) * J_ + jbase + jcol] = a + b + bias[jbase + jcol];
    }
}

extern "C" void kernel_launch(void* const* d_in, const int* in_sizes, int n_in,
                              void* d_out, int out_size, void* d_ws, size_t ws_size,
                              hipStream_t stream) {
    const float* x    = (const float*)d_in[0];
    const float* w    = (const float*)d_in[1];
    const float* bias = (const float*)d_in[2];
    float* out = (float*)d_out;

    dim3 grid(512);   // 2 j-halves x 256 n-groups, XCD-swizzled in-kernel
    mam_fused6<<<grid, 512, 0, stream>>>(x, w, bias, out);
}